// Round 4
// baseline (61.975 us; speedup 1.0000x reference)
//
#include <hip/hip_runtime.h>

// DropBlock, two-phase:
//   K1: per-channel dilated drop-bitmask (64 rows x u64) -> d_ws   [128 KB]
//   K2: pure streaming apply: out = bit ? 0 : x
//       grid-stride with stride == 2 mask periods -> per-thread mask bits are
//       loop-invariant (hoisted); fully unrolled for load batching (MLP).

constexpr int C = 256;

typedef float f32x4 __attribute__((ext_vector_type(4)));

// ---- K1: mask build. One block per channel, 256 threads. ----
__global__ __launch_bounds__(256)
void mask_kernel(const float* __restrict__ noise,
                 unsigned long long* __restrict__ maskbits) {
    const int c = blockIdx.x;
    __shared__ unsigned long long rowS[64];

    const int tid = threadIdx.x;
    const int lane = tid & 63;
    const int wv = tid >> 6;

    // gamma in double, matching the f64 numpy reference comparison
    const double gamma = (1.0 - 0.9) / (7.0 * 7.0) * (64.0 * 64.0) / (58.0 * 58.0);

    const float* nc = noise + (size_t)c * 4096;
    for (int h = wv; h < 64; h += 4) {
        float v = nc[h * 64 + lane];
        bool center = ((double)v < gamma) && (h >= 3) && (h <= 60)
                                          && (lane >= 3) && (lane <= 60);
        unsigned long long bits = __ballot(center);
        unsigned long long t = bits | (bits << 1) | (bits >> 1);
        unsigned long long s = t | (t << 2) | (t >> 2);
        if (lane == 0) rowS[h] = s;
    }
    __syncthreads();

    if (tid < 64) {
        int lo = tid - 3; if (lo < 0) lo = 0;
        int hi = tid + 3; if (hi > 63) hi = 63;
        unsigned long long d = 0;
        for (int hh = lo; hh <= hi; ++hh) d |= rowS[hh];
        maskbits[c * 64 + tid] = d;   // 1 = drop
    }
}

// ---- K2: streaming apply, mask hoisted, fully unrolled ----
// n4 = 32*256*64*64/4 = 8388608 = 2048 blocks * 256 threads * 16 iters exactly.
// stride 524288 f32x4 = 2 mask periods (262144) -> mask bits loop-invariant.
__global__ __launch_bounds__(256)
void apply_kernel(const f32x4* __restrict__ x,
                  const unsigned long long* __restrict__ maskbits,
                  f32x4* __restrict__ out) {
    const int base = blockIdx.x * 256 + threadIdx.x;
    const unsigned long long b = maskbits[(base >> 4) & 16383];
    const int w0 = (base & 15) << 2;
    const bool d0 = (b >> (w0 + 0)) & 1ull;
    const bool d1 = (b >> (w0 + 1)) & 1ull;
    const bool d2 = (b >> (w0 + 2)) & 1ull;
    const bool d3 = (b >> (w0 + 3)) & 1ull;
    #pragma unroll
    for (int j = 0; j < 16; ++j) {
        const int i = base + j * 524288;
        f32x4 v = x[i];
        v.x = d0 ? 0.0f : v.x;
        v.y = d1 ? 0.0f : v.y;
        v.z = d2 ? 0.0f : v.z;
        v.w = d3 ? 0.0f : v.w;
        out[i] = v;
    }
}

extern "C" void kernel_launch(void* const* d_in, const int* in_sizes, int n_in,
                              void* d_out, int out_size, void* d_ws, size_t ws_size,
                              hipStream_t stream) {
    const float* x = (const float*)d_in[0];
    const float* noise = (const float*)d_in[1];
    float* out = (float*)d_out;
    unsigned long long* maskbits = (unsigned long long*)d_ws;  // 16384 u64 = 128 KB

    mask_kernel<<<C, 256, 0, stream>>>(noise, maskbits);
    apply_kernel<<<2048, 256, 0, stream>>>((const f32x4*)x, maskbits, (f32x4*)out);
}

// Round 5
// 55.546 us; speedup vs baseline: 1.1157x; 1.1157x over previous
//
#include <hip/hip_runtime.h>

// DropBlock, fused single kernel, barrier-free.
// Mask is built wave-locally: lane l owns mask row l (64 bits in a u64).
//   centers: noise < gamma, zeroed within 3 of border
//   dilation: row smear = bit shifts; column smear = 4 wave shuffles (OR)
// Then pure streaming: out = bit ? 0 : x, f32x4, no LDS, no __syncthreads.

constexpr int C = 256;

typedef float f32x4 __attribute__((ext_vector_type(4)));

static __device__ __forceinline__ unsigned long long shflup64(unsigned long long v, int d) {
    unsigned lo = __shfl_up((unsigned)v, d);
    unsigned hi = __shfl_up((unsigned)(v >> 32), d);
    return ((unsigned long long)hi << 32) | lo;
}
static __device__ __forceinline__ unsigned long long shfldn64(unsigned long long v, int d) {
    unsigned lo = __shfl_down((unsigned)v, d);
    unsigned hi = __shfl_down((unsigned)(v >> 32), d);
    return ((unsigned long long)hi << 32) | lo;
}
static __device__ __forceinline__ unsigned long long shfl64(unsigned long long v, int src) {
    unsigned lo = __shfl((unsigned)v, src);
    unsigned hi = __shfl((unsigned)(v >> 32), src);
    return ((unsigned long long)hi << 32) | lo;
}

__global__ __launch_bounds__(256)
void dropblock_kernel(const float* __restrict__ x,
                      const float* __restrict__ noise,
                      float* __restrict__ out) {
    const int c = blockIdx.x;       // channel
    const int slice = blockIdx.y;   // batch slice 0..7
    const int tid = threadIdx.x;
    const int lane = tid & 63;

    // gamma in double (validated in R1: absmax 0 vs numpy ref)
    const double gamma = (1.0 - 0.9) / (7.0 * 7.0) * (64.0 * 64.0) / (58.0 * 58.0);

    // ---- wave-local mask build: lane l = row l ----
    unsigned long long bits = 0;
    const f32x4* rowp = (const f32x4*)(noise + (size_t)c * 4096 + lane * 64);
    #pragma unroll
    for (int j = 0; j < 16; ++j) {
        f32x4 v = rowp[j];
        bits |= ((double)v.x < gamma ? 1ull : 0ull) << (4 * j + 0);
        bits |= ((double)v.y < gamma ? 1ull : 0ull) << (4 * j + 1);
        bits |= ((double)v.z < gamma ? 1ull : 0ull) << (4 * j + 2);
        bits |= ((double)v.w < gamma ? 1ull : 0ull) << (4 * j + 3);
    }
    // border zeroing: centers only for rows/cols in [3,60]
    bits &= 0x1FFFFFFFFFFFFFF8ull;              // cols 3..60
    if (lane < 3 || lane > 60) bits = 0;        // rows 3..60
    // row dilation +-3 (log smear)
    unsigned long long t = bits | (bits << 1) | (bits >> 1);
    unsigned long long s = t | (t << 2) | (t >> 2);
    // column dilation +-3 via shuffles; OOB shfl returns own value (harmless under OR)
    unsigned long long a = s | shflup64(s, 1) | shfldn64(s, 1);
    unsigned long long d = a | shflup64(a, 2) | shfldn64(a, 2);
    // lane l now holds drop-bits for row l (1 = drop)

    // ---- hoist per-thread mask bits (loop-invariant across images) ----
    const int w0 = (tid & 15) << 2;             // 16 f32x4 per row
    const int h0 = tid >> 4;                    // rows h0, h0+16, h0+32, h0+48
    const unsigned b0m = (unsigned)(shfl64(d, h0 +  0) >> w0) & 0xF;
    const unsigned b1m = (unsigned)(shfl64(d, h0 + 16) >> w0) & 0xF;
    const unsigned b2m = (unsigned)(shfl64(d, h0 + 32) >> w0) & 0xF;
    const unsigned b3m = (unsigned)(shfl64(d, h0 + 48) >> w0) & 0xF;
    const unsigned bm[4] = {b0m, b1m, b2m, b3m};

    // ---- streaming apply: 4 images x 4 chunks of 4KB ----
    const int bb0 = slice * 4;
    #pragma unroll
    for (int bb = 0; bb < 4; ++bb) {
        const size_t img = (size_t)(bb0 + bb) * C + c;
        const f32x4* xi = (const f32x4*)x + img * 1024;
        f32x4* oi = (f32x4*)out + img * 1024;
        #pragma unroll
        for (int k = 0; k < 4; ++k) {
            const int i = tid + k * 256;
            f32x4 v = xi[i];
            const unsigned m = bm[k];
            v.x = (m & 1u) ? 0.0f : v.x;
            v.y = (m & 2u) ? 0.0f : v.y;
            v.z = (m & 4u) ? 0.0f : v.z;
            v.w = (m & 8u) ? 0.0f : v.w;
            oi[i] = v;
        }
    }
}

extern "C" void kernel_launch(void* const* d_in, const int* in_sizes, int n_in,
                              void* d_out, int out_size, void* d_ws, size_t ws_size,
                              hipStream_t stream) {
    const float* x = (const float*)d_in[0];
    const float* noise = (const float*)d_in[1];
    float* out = (float*)d_out;

    dim3 grid(C, 8);   // 256 channels x 8 batch-slices, 4 images each
    dropblock_kernel<<<grid, 256, 0, stream>>>(x, noise, out);
}

// Round 6
// 52.379 us; speedup vs baseline: 1.1832x; 1.0605x over previous
//
#include <hip/hip_runtime.h>

// DropBlock fused: LDS mask build (R1 form, measured-cheap) + batched streaming.
// Apply phase loads 8 f32x4 into registers FIRST, then 8 masked stores --
// forcing 8 loads in flight per thread (MLP), no load->store serial chain.

constexpr int C = 256;

typedef float f32x4 __attribute__((ext_vector_type(4)));

__global__ __launch_bounds__(256)
void dropblock_kernel(const float* __restrict__ x,
                      const float* __restrict__ noise,
                      float* __restrict__ out) {
    const int c = blockIdx.x;       // channel 0..255
    const int slice = blockIdx.y;   // batch slice 0..15 (2 images each)

    __shared__ unsigned long long rowS[64];
    __shared__ unsigned long long dil[64];

    const int tid = threadIdx.x;
    const int lane = tid & 63;
    const int wv = tid >> 6;

    // gamma in double, matches f64 numpy reference comparison (absmax 0 in R1)
    const double gamma = (1.0 - 0.9) / (7.0 * 7.0) * (64.0 * 64.0) / (58.0 * 58.0);

    // ---- Phase 1: centers + row dilation (each wave: 16 rows) ----
    const float* nc = noise + (size_t)c * 4096;
    for (int h = wv; h < 64; h += 4) {
        float v = nc[h * 64 + lane];
        bool center = ((double)v < gamma) && (h >= 3) && (h <= 60)
                                          && (lane >= 3) && (lane <= 60);
        unsigned long long bits = __ballot(center);
        unsigned long long t = bits | (bits << 1) | (bits >> 1);
        unsigned long long s = t | (t << 2) | (t >> 2);
        if (lane == 0) rowS[h] = s;
    }
    __syncthreads();

    // ---- Phase 2: column dilation ----
    if (tid < 64) {
        int lo = tid - 3; if (lo < 0) lo = 0;
        int hi = tid + 3; if (hi > 63) hi = 63;
        unsigned long long d = 0;
        for (int hh = lo; hh <= hi; ++hh) d |= rowS[hh];
        dil[tid] = d;
    }
    __syncthreads();

    // ---- Phase 3: batched apply. 2 images, 4 f32x4 each = 8 loads then 8 stores.
    const int b0 = slice * 2;
    const size_t img0 = (size_t)(b0 + 0) * C + c;
    const size_t img1 = (size_t)(b0 + 1) * C + c;
    const f32x4* x0 = (const f32x4*)x + img0 * 1024;
    const f32x4* x1 = (const f32x4*)x + img1 * 1024;
    f32x4* o0 = (f32x4*)out + img0 * 1024;
    f32x4* o1 = (f32x4*)out + img1 * 1024;

    // per-thread mask nibbles for its 4 chunk positions (loop-invariant)
    unsigned m[4];
    #pragma unroll
    for (int k = 0; k < 4; ++k) {
        const int i = tid + k * 256;
        m[k] = (unsigned)(dil[i >> 4] >> ((i & 15) << 2)) & 0xF;
    }

    f32x4 v[8];
    #pragma unroll
    for (int k = 0; k < 4; ++k) v[k]     = x0[tid + k * 256];
    #pragma unroll
    for (int k = 0; k < 4; ++k) v[k + 4] = x1[tid + k * 256];

    #pragma unroll
    for (int k = 0; k < 8; ++k) {
        const unsigned mk = m[k & 3];
        v[k].x = (mk & 1u) ? 0.0f : v[k].x;
        v[k].y = (mk & 2u) ? 0.0f : v[k].y;
        v[k].z = (mk & 4u) ? 0.0f : v[k].z;
        v[k].w = (mk & 8u) ? 0.0f : v[k].w;
    }

    #pragma unroll
    for (int k = 0; k < 4; ++k) o0[tid + k * 256] = v[k];
    #pragma unroll
    for (int k = 0; k < 4; ++k) o1[tid + k * 256] = v[k + 4];
}

extern "C" void kernel_launch(void* const* d_in, const int* in_sizes, int n_in,
                              void* d_out, int out_size, void* d_ws, size_t ws_size,
                              hipStream_t stream) {
    const float* x = (const float*)d_in[0];
    const float* noise = (const float*)d_in[1];
    float* out = (float*)d_out;

    dim3 grid(C, 16);   // 256 channels x 16 slices, 2 images each
    dropblock_kernel<<<grid, 256, 0, stream>>>(x, noise, out);
}